// Round 10
// baseline (119.314 us; speedup 1.0000x reference)
//
#include <hip/hip_runtime.h>
#include <math.h>

// EvidNets R23: 256 blocks x 1024 thr (16 waves = 4/SIMD), 64 samples x ALL
// 512 protos, two 256-proto phases. Two dispatches, no cross-block sync.
//   A_c(b) = prod_k (1 - s_kb*(1-U_kc)),  N(b) = prod_k (1 - s_kb)
//   out[b][c<20] = (A_c-N)/K, out[b][20] = N/K, K = sum_c A_c - 19N
//   s_kb = alphap_k * exp(-gamma_k^2*(0.5*(|W_k|^2+|x_b|^2) - W_k.x_b))
// R22 post-mortem: 16-wave occupancy worked but 512x32-sample tiling doubled
// B traffic to 256MB (every block reads all 512KB packed W) -> +5us net.
// R23 keeps R21's traffic shape (256 blocks x 64 samples: B 128MB, X once)
// AND R22's occupancy: 16 waves in the SAME block. Wave-job = (proto-tile
// i = w>>1, sample-half s = w&1) per phase (round-0's proven pairing; pair
// shares the B-tile -> L1 reuse). Per phase: 1 MFMA pass (48 MFMA), write
// own swizzled s-band (own rows x own protos -> self-contained, no intra-
// phase barrier), combine all-64-lane: lane = (sample pl, proto-half h),
// 21 classes x 16 protos, shfl_xor(32) merge. VS slices in LDS per-tile
// (pair writes idempotent identical values; each wave writes before reads).
// ONE barrier between phases (vsl+sc rewrite), B5 before endgame.
// LDS 148.6KB = A 64 + sc 64 + vsl 20 -> 1 block/CU but 16 waves/CU.
// Live VGPR ~116 <= hard 128 cap; amdgpu_waves_per_eu(4,4) pins allocator
// (R15 redux guard). Tripwire: VGPR=64 or FETCH >> 10.7MB = cap returned.

#define NBATCH 16384
#define ND     256
#define NP     512
#define NCLS   20
#define OC     21

typedef short  short8  __attribute__((ext_vector_type(8)));
typedef short  short4v __attribute__((ext_vector_type(4)));
typedef unsigned short ushort8 __attribute__((ext_vector_type(8)));
typedef float  f32x16  __attribute__((ext_vector_type(16)));

// ---- workspace layout (bytes) ----
#define OFF_PWH 0u
#define OFF_PWL 262144u
#define OFF_VS  524288u                 // float VS[21][512] = 1-U (row 20 = 1)
#define OFF_WQ  567296u
#define OFF_AP  569344u
#define OFF_G2  571392u

__device__ __forceinline__ unsigned short f2bf_rn(float f) {
  unsigned int u = __float_as_uint(f);
  unsigned int r = (u + 0x7FFFu + ((u >> 16) & 1u)) >> 16;   // RNE (finite inputs)
  return (unsigned short)r;
}
__device__ __forceinline__ float bf2f(unsigned short h) {
  return __uint_as_float(((unsigned int)h) << 16);
}

// Combined prep: blocks 0..63 pack W[512][256] -> MFMA B-fragment order hi/lo
// bf16 + row sum-squares; blocks 64..65 build VS/AP/G2 tables.
// frag elem (tile,step,lane,j) = src[tile*32+(lane&31)][step*16+8*(lane>>5)+j]
__global__ __launch_bounds__(256)
void prep(const float* __restrict__ Wsrc, const float* __restrict__ BETA,
          const float* __restrict__ alpha, const float* __restrict__ gamma,
          unsigned short* __restrict__ dh, unsigned short* __restrict__ dl,
          float* __restrict__ sq, float* __restrict__ VS,
          float* __restrict__ AP, float* __restrict__ G2)
{
  const int bid = blockIdx.x;
  if (bid < 64) {                      // ---- pack W ----
    const int tid = bid * 256 + threadIdx.x;
    const int row = tid >> 5, seg = tid & 31;
    const float4* s4 = (const float4*)(Wsrc + (size_t)row * ND + seg * 8);
    const float4 a = s4[0], b = s4[1];
    const float v[8] = {a.x, a.y, a.z, a.w, b.x, b.y, b.z, b.w};
    ushort8 hv, lv;
    float ssq = 0.f;
    #pragma unroll
    for (int j = 0; j < 8; ++j) {
      ssq = fmaf(v[j], v[j], ssq);
      const unsigned short hh = f2bf_rn(v[j]);
      hv[j] = hh;
      lv[j] = f2bf_rn(v[j] - bf2f(hh));
    }
    const int tile = row >> 5, m = row & 31, step = seg >> 1, r = seg & 1;
    const size_t cidx = (size_t)(tile * 16 + step) * 64 + m + 32 * r;
    *(ushort8*)(dh + cidx * 8) = hv;
    *(ushort8*)(dl + cidx * 8) = lv;
    #pragma unroll
    for (int off = 1; off < 32; off <<= 1) ssq += __shfl_xor(ssq, off, 64);
    if (seg == 0) sq[row] = ssq;
  } else {                             // ---- scalar tables ----
    const int k = (bid - 64) * 256 + threadIdx.x;
    if (k >= NP) return;
    float bv[NCLS], bs = 0.f;
    #pragma unroll
    for (int c = 0; c < NCLS; ++c) { bv[c] = BETA[k * NCLS + c]; bs = fmaf(bv[c], bv[c], bs); }
    const float binv = 1.f / bs;
    #pragma unroll
    for (int c = 0; c < NCLS; ++c) VS[c * NP + k] = 1.f - bv[c] * bv[c] * binv;
    VS[NCLS * NP + k] = 1.f;
    AP[k] = 0.99f / (1.f + __expf(-alpha[k]));
    const float g = gamma[k];
    G2[k] = g * g;
  }
}

// One MFMA pass over sample-half sh: 32x32 tile, K=256, hi/lo split in TWO
// acc chains (accA = ah*bh; accB = ah*bl + al*bh), depth-4 B ring (4 waves/
// SIMD TLP hides L2), epilogue s -> sout[16].
__device__ __forceinline__ void mfma_pass4(
    const short* __restrict__ Ah, const short* __restrict__ Al,
    const short8* __restrict__ bHc, const short8* __restrict__ bLc,
    const int lane, const int sh, const float* __restrict__ xqs,
    const float wqk, const float apk, const float g2k, float* __restrict__ sout)
{
  short8 wbh[4], wbl[4];
  #pragma unroll
  for (int p = 0; p < 4; ++p) { wbh[p] = bHc[p * 64]; wbl[p] = bLc[p * 64]; }

  f32x16 accA, accB;
  #pragma unroll
  for (int i = 0; i < 16; ++i) { accA[i] = 0.f; accB[i] = 0.f; }
  const short8* aH = (const short8*)Ah + (size_t)sh * 1024 + lane;
  const short8* aL = (const short8*)Al + (size_t)sh * 1024 + lane;
  #pragma unroll
  for (int step = 0; step < 16; ++step) {
    const short8 ah = aH[step * 64], al = aL[step * 64];
    const short8 bh = wbh[step & 3], bl = wbl[step & 3];
    if (step < 12) {
      wbh[step & 3] = bHc[(step + 4) * 64];
      wbl[step & 3] = bLc[(step + 4) * 64];
    }
    accA = __builtin_amdgcn_mfma_f32_32x32x16_bf16(ah, bh, accA, 0, 0, 0);
    accB = __builtin_amdgcn_mfma_f32_32x32x16_bf16(ah, bl, accB, 0, 0, 0);
    accB = __builtin_amdgcn_mfma_f32_32x32x16_bf16(al, bh, accB, 0, 0, 0);
  }
  // C/D: col(n)=lane&31 (proto), row(m)=(rg&3)+8*(rg>>2)+4*(lane>>5)
  const int h = lane >> 5;
  #pragma unroll
  for (int rg = 0; rg < 16; ++rg) {
    const int   m  = (rg & 3) + 8 * (rg >> 2) + 4 * h;
    const float dv = 0.5f * (wqk + xqs[sh * 32 + m]) - (accA[rg] + accB[rg]);
    sout[rg] = apk * __expf(-g2k * dv);
  }
}

// ---- main: 256 blocks x 1024 thr (16 waves, 4/SIMD). Block bx: samples
// bx*64..+64, ALL 512 protos in two 256-proto phases. Wave w = (tile i=w>>1,
// sample-half s=w&1). LDS: A 64KB + sc[64][256] 64KB + vsl[8][20][32] 20KB
// + xqs; endgame E/R/kv alias the A region after B5. ----
__global__ __launch_bounds__(1024) __attribute__((amdgpu_waves_per_eu(4, 4)))
void evid64w(const float* __restrict__ X,
             const unsigned short* __restrict__ PWH, const unsigned short* __restrict__ PWL,
             const float* __restrict__ VS, const float* __restrict__ WQ,
             const float* __restrict__ AP, const float* __restrict__ G2,
             float* __restrict__ OUT)
{
  __shared__ __align__(16) char pool[131072];
  __shared__ float vsl[8 * NCLS * 32];   // per-tile VS slices (20KB)
  __shared__ float xqs[64];
  short* Ah = (short*)pool;            // 16384 shorts = 32KB
  short* Al = (short*)(pool + 32768);  // 16384 shorts = 32KB
  float* sc = (float*)(pool + 65536);  // 64 x 256 floats = 64KB (per phase)

  const int t    = threadIdx.x;
  const int lane = t & 63;
  const int w    = __builtin_amdgcn_readfirstlane(t >> 6);  // wave 0..15
  const int i    = w >> 1;                                  // proto tile 0..7
  const int s    = w & 1;                                   // sample half
  const int bx   = blockIdx.x;
  const int bbase = bx * 64;
  const int pl = lane & 31, h = lane >> 5;

  // ---- stage: 64 X rows f32 -> hi/lo bf16 fragments (16 lanes/row, once) ----
  {
    const int r  = t >> 4;             // 0..63
    const int sg = t & 15;
    const int rsh = r >> 5, rm = r & 31;
    const float* xrow = X + (size_t)(bbase + r) * ND;
    float ssq = 0.f;
    #pragma unroll
    for (int it = 0; it < 4; ++it) {
      const int c0 = it * 64 + sg * 4;
      const float4 v = *(const float4*)(xrow + c0);
      const float vv[4] = {v.x, v.y, v.z, v.w};
      short4v h4, l4;
      #pragma unroll
      for (int j = 0; j < 4; ++j) {
        ssq = fmaf(vv[j], vv[j], ssq);
        const unsigned short hh = f2bf_rn(vv[j]);
        h4[j] = (short)hh;
        l4[j] = (short)f2bf_rn(vv[j] - bf2f(hh));
      }
      const int step = c0 >> 4, hf = (c0 >> 3) & 1, j0 = c0 & 7;
      const int base = (((rsh * 16 + step) * 64) + (rm + 32 * hf)) * 8 + j0;
      *(short4v*)&Ah[base] = h4;
      *(short4v*)&Al[base] = l4;
    }
    ssq += __shfl_xor(ssq, 1, 64);
    ssq += __shfl_xor(ssq, 2, 64);
    ssq += __shfl_xor(ssq, 4, 64);
    ssq += __shfl_xor(ssq, 8, 64);
    if (sg == 0) xqs[r] = ssq;
  }
  __syncthreads();                     // B1: A-frags + xqs ready

  float Apc[OC];
  #pragma unroll
  for (int c = 0; c < OC; ++c) Apc[c] = 1.0f;

  float* vw = vsl + i * (NCLS * 32);   // this tile's VS slice (pair-shared)

  // ---- two proto-phases; wave (i,s): tile ph*8+i, sample rows s*32..+32 ----
  #pragma unroll
  for (int ph = 0; ph < 2; ++ph) {
    if (ph == 1) __syncthreads();      // B3: phase-0 vsl/sc reads done

    // stage tile i's VS slice (pair writes IDENTICAL values -> benign;
    // each wave writes before its own reads; hidden under MFMA below)
    {
      const float* vg = VS + ph * 256 + i * 32;     // + c*NP
      #pragma unroll
      for (int q = 0; q < 10; ++q) {
        const int idx = q * 64 + lane;              // 0..639 = c*32+j
        vw[idx] = vg[(idx >> 5) * NP + (idx & 31)];
      }
    }

    const int kp = ph * 256 + i * 32 + pl;          // global proto id
    const float wqk = WQ[kp], apk = AP[kp], g2k = G2[kp];
    const short8* bHc = (const short8*)PWH + (size_t)(ph * 8 + i) * 1024 + lane;
    const short8* bLc = (const short8*)PWL + (size_t)(ph * 8 + i) * 1024 + lane;

    float sreg[16];
    mfma_pass4(Ah, Al, bHc, bLc, lane, s, xqs, wqk, apk, g2k, sreg);

    // write s-band: rows s*32+m (own), cols band of tile i (own):
    // sc[b][(i*32+pl + 4b) & 255]
    {
      const int p = i * 32 + pl;
      #pragma unroll
      for (int rg = 0; rg < 16; ++rg) {
        const int m = (rg & 3) + 8 * (rg >> 2) + 4 * h;
        const int b = s * 32 + m;
        sc[b * 256 + ((p + 4 * b) & 255)] = sreg[rg];
      }
    }
    // no intra-phase barrier: band is wave-private (own rows x own protos)

    // ---- combine: lane = (sample pl of own half, proto-half h) ----
    {
      const int b = s * 32 + pl;                    // own sample row
      float sv[16];
      const int cb = i * 32 + h * 16 + 4 * b;       // swizzled col base
      #pragma unroll
      for (int q = 0; q < 4; ++q)
        *(float4*)&sv[4 * q] = *(const float4*)&sc[b * 256 + ((cb + 4 * q) & 255)];
      // sv[4q+r] = s[b][proto i*32 + h*16 + 4q + r]

      const float* vb = vw + h * 16;                // per-lane LDS addr (ok)
      #pragma unroll 4
      for (int c = 0; c < NCLS; ++c) {
        const float* vp = vb + c * 32;
        float f4[4];
        #pragma unroll
        for (int j = 0; j < 4; ++j) f4[j] = fmaf(-sv[j], vp[j], 1.0f);
        #pragma unroll
        for (int j = 4; j < 16; ++j) f4[j & 3] *= fmaf(-sv[j], vp[j], 1.0f);
        Apc[c] *= (f4[0] * f4[1]) * (f4[2] * f4[3]);
      }
      { // c = 20: VS row == 1.0 -> f = 1 - s
        float f4[4];
        #pragma unroll
        for (int j = 0; j < 4; ++j) f4[j] = 1.0f - sv[j];
        #pragma unroll
        for (int j = 4; j < 16; ++j) f4[j & 3] *= (1.0f - sv[j]);
        Apc[NCLS] *= (f4[0] * f4[1]) * (f4[2] * f4[3]);
      }
    }
  }
  // merge proto-halves: lanes pl / pl+32 hold the two 16-proto partials
  #pragma unroll
  for (int c = 0; c < OC; ++c) Apc[c] *= __shfl_xor(Apc[c], 32, 64);

  __syncthreads();                     // B5: all waves done with A/sc regions

  // ---- endgame: reduce 8 tile-partials per sample, normalize, OUT ----
  float* E  = (float*)pool;            // 8*21*64 floats = 42KB (A dead)
  float* R  = (float*)(pool + 43008);  // 21*64 floats
  float* kv = (float*)(pool + 48384);  // 64 floats
  if (h == 0) {
    const int b = s * 32 + pl;
    #pragma unroll
    for (int c = 0; c < OC; ++c) E[(i * OC + c) * 64 + b] = Apc[c];
  }
  __syncthreads();
  {
    const int b = t & 63, j = t >> 6;  // j = 0..15
    for (int c = j; c < OC; c += 16) {
      float p = E[c * 64 + b];
      #pragma unroll
      for (int ww = 1; ww < 8; ++ww) p *= E[(ww * OC + c) * 64 + b];
      R[c * 64 + b] = p;
    }
  }
  __syncthreads();
  if (t < 64) {
    const float Nv = R[NCLS * 64 + t];
    float K = Nv;
    #pragma unroll
    for (int c = 0; c < NCLS; ++c) K += R[c * 64 + t] - Nv;
    kv[t] = 1.0f / K;
  }
  __syncthreads();
  for (int idx = t; idx < 64 * OC; idx += 1024) {
    const int b = idx / OC, c = idx - b * OC;
    const float Nv = R[NCLS * 64 + b];
    const float ik = kv[b];
    OUT[(size_t)bx * 64 * OC + idx] = (c < NCLS) ? (R[c * 64 + b] - Nv) * ik : Nv * ik;
  }
}

extern "C" void kernel_launch(void* const* d_in, const int* in_sizes, int n_in,
                              void* d_out, int out_size, void* d_ws, size_t ws_size,
                              hipStream_t stream) {
  (void)in_sizes; (void)n_in; (void)out_size; (void)ws_size;
  const float* X     = (const float*)d_in[0];
  const float* Wm    = (const float*)d_in[1];
  const float* BETA  = (const float*)d_in[2];
  const float* ALPHA = (const float*)d_in[3];
  const float* GAMMA = (const float*)d_in[4];
  float* OUT = (float*)d_out;

  char* ws = (char*)d_ws;
  unsigned short* PWH = (unsigned short*)(ws + OFF_PWH);
  unsigned short* PWL = (unsigned short*)(ws + OFF_PWL);
  float* VS = (float*)(ws + OFF_VS);
  float* WQ = (float*)(ws + OFF_WQ);
  float* AP = (float*)(ws + OFF_AP);
  float* G2 = (float*)(ws + OFF_G2);

  hipLaunchKernelGGL(prep, dim3(66), dim3(256), 0, stream,
                     Wm, BETA, ALPHA, GAMMA, PWH, PWL, WQ, VS, AP, G2);
  hipLaunchKernelGGL(evid64w, dim3(NBATCH / 64), dim3(1024), 0, stream,
                     X, PWH, PWL, VS, WQ, AP, G2, OUT);
}